// Round 9
// baseline (588.182 us; speedup 1.0000x reference)
//
#include <hip/hip_runtime.h>

#define N_NODES 20000
#define N_EDGES 320000
#define HID 64
#define MDIM 8
#define ROW 512            // HID*MDIM elements per node row (layout: [n][m][c])
#define NM 160000.0f       // N_NODES*MDIM
#define NCHUNK 79          // ceil(20000/256)
#define NSHADOW 16         // shadow copies per layer
#define ZSTRIDE 72         // shorts per nm-row (64 + 8 pad)
#define NBLK 1250          // k_layer grid (16 nodes/block)

typedef unsigned int uint;
typedef unsigned short ushort;
typedef __attribute__((ext_vector_type(8))) short bf16x8;
typedef __attribute__((ext_vector_type(4))) float f32x4;

union U4B8 { uint4 u; bf16x8 b; };

__device__ __forceinline__ float bflo(uint u) { return __uint_as_float(u << 16); }
__device__ __forceinline__ float bfhi(uint u) { return __uint_as_float(u & 0xffff0000u); }
__device__ __forceinline__ uint f2bf(float f) {   // round-to-nearest-even
    uint u = __float_as_uint(f);
    return (u + 0x7fffu + ((u >> 16) & 1u)) >> 16;
}
__device__ __forceinline__ uint pack2(float lo, float hi) { return f2bf(lo) | (f2bf(hi) << 16); }

// ---------------- CSR build ----------------
__global__ __launch_bounds__(256) void k_hist(const int* __restrict__ dst, int* __restrict__ deg) {
    int e = blockIdx.x * 256 + threadIdx.x;
    if (e < N_EDGES) atomicAdd(&deg[dst[e]], 1);
}

__global__ __launch_bounds__(256) void k_csum(const int* __restrict__ deg, int* __restrict__ csum) {
    __shared__ int r[256];
    int t = threadIdx.x, i = blockIdx.x * 256 + t;
    r[t] = (i < N_NODES) ? deg[i] : 0;
    __syncthreads();
    for (int s = 128; s > 0; s >>= 1) { if (t < s) r[t] += r[t + s]; __syncthreads(); }
    if (t == 0) csum[blockIdx.x] = r[0];
}

__global__ __launch_bounds__(128) void k_cscan(const int* __restrict__ csum, int* __restrict__ chunkoff) {
    __shared__ int s[128];
    int t = threadIdx.x;
    s[t] = (t < NCHUNK) ? csum[t] : 0;
    __syncthreads();
    if (t == 0) { int run = 0; for (int j = 0; j < NCHUNK; ++j) { int x = s[j]; s[j] = run; run += x; } }
    __syncthreads();
    if (t < NCHUNK) chunkoff[t] = s[t];
}

__global__ __launch_bounds__(256) void k_chunkscan(const int* __restrict__ deg, const int* __restrict__ chunkoff,
                                                   int* __restrict__ offs) {
    __shared__ int sd[256];
    int t = threadIdx.x, i = blockIdx.x * 256 + t;
    int v = (i < N_NODES) ? deg[i] : 0;
    sd[t] = v;
    __syncthreads();
    for (int off = 1; off < 256; off <<= 1) {
        int x = (t >= off) ? sd[t - off] : 0;
        __syncthreads();
        sd[t] += x;
        __syncthreads();
    }
    if (i < N_NODES) offs[i] = sd[t] - v + chunkoff[blockIdx.x];
}

__global__ __launch_bounds__(256) void k_fill(const int* __restrict__ src, const int* __restrict__ dst,
                                              const int* __restrict__ offs, int* __restrict__ cursor,
                                              int* __restrict__ esrc) {
    int e = blockIdx.x * 256 + threadIdx.x;
    if (e < N_EDGES) {
        int d = dst[e];
        int p = atomicAdd(&cursor[d], 1);
        esrc[offs[d] + p] = src[e];
    }
}

// ---------------- degree-balanced permutation: counting sort, degree DESCENDING
__global__ __launch_bounds__(256) void k_dhist(const int* __restrict__ deg, int* __restrict__ bins) {
    __shared__ int lb[64];
    int t = threadIdx.x;
    if (t < 64) lb[t] = 0;
    __syncthreads();
    int n = blockIdx.x * 256 + t;
    if (n < N_NODES) {
        int d = deg[n]; d = d > 63 ? 63 : d;
        atomicAdd(&lb[63 - d], 1);
    }
    __syncthreads();
    if (t < 64 && lb[t]) atomicAdd(&bins[t], lb[t]);
}

__global__ __launch_bounds__(64) void k_dscan(const int* __restrict__ bins, int* __restrict__ bincur) {
    if (threadIdx.x == 0) {
        int run = 0;
        for (int j = 0; j < 64; ++j) { bincur[j] = run; run += bins[j]; }
    }
}

__global__ __launch_bounds__(256) void k_dscatter(const int* __restrict__ deg, int* __restrict__ bincur,
                                                  int* __restrict__ perm) {
    int n = blockIdx.x * 256 + threadIdx.x;
    if (n < N_NODES) {
        int d = deg[n]; d = d > 63 ? 63 : d;
        int pos = atomicAdd(&bincur[63 - d], 1);
        perm[pos] = n;
    }
}

// ---------------- pre-pack weights into MFMA A-fragment order (bf16)
// slots 0..4095: layers 1..4, {w1,w2} x 512 ; slots 4096..4607: layer-0 w2
__global__ __launch_bounds__(256) void k_prep(const float* __restrict__ w1, const float* __restrict__ w2,
                                              uint4* __restrict__ wfrag) {
    int id = blockIdx.x * 256 + threadIdx.x;   // 4608 total
    if (id >= 4608) return;
    const float* W;
    int s;
    if (id < 4096) {
        int layer = id >> 10;          // 0..3 -> model layer layer+1
        int rem = id & 1023;
        int which = rem >> 9;          // 0: w1, 1: w2
        s = rem & 511;
        W = which ? &w2[(size_t)(layer + 1) * 4096] : &w1[(size_t)layer * 4096];
    } else {
        s = id - 4096;
        W = w2;                        // layer-0 w2
    }
    int f = s >> 6, l = s & 63;
    int o = (f >> 1) * 16 + (l & 15);
    int c0 = (f & 1) * 32 + (l >> 4) * 8;
    const float* p = &W[o * 64 + c0];
    uint4 a;
    a.x = pack2(p[0], p[1]); a.y = pack2(p[2], p[3]);
    a.z = pack2(p[4], p[5]); a.w = pack2(p[6], p[7]);
    wfrag[id] = a;
}

// ---------------- fused layer 0 (MFMA): gather x (C=1) + rank-1 linear1 in B-frag regs + MFMA linear2
// block = 4 waves x 4 nodes (degree-striped via perm)
__global__ __launch_bounds__(256) void k_layer0(const float* __restrict__ x, const int* __restrict__ offs,
                                                const int* __restrict__ deg, const int* __restrict__ esrc,
                                                const int* __restrict__ perm,
                                                const float* __restrict__ W10, const float* __restrict__ B1,
                                                const uint4* __restrict__ w2f0, const float* __restrict__ B2,
                                                ushort* __restrict__ zout, float* __restrict__ shadow) {
    __shared__ uint4 w2s[512];
    __shared__ __align__(16) ushort zbuf[128 * ZSTRIDE];
    int tid = threadIdx.x;
    for (int s2 = tid; s2 < 512; s2 += 256) w2s[s2] = w2f0[s2];
    __syncthreads();
    int w = tid >> 6, t = tid & 63;
    int g = t >> 3, m = t & 7;
    int nodes[4];
    #pragma unroll
    for (int i = 0; i < 4; ++i) nodes[i] = perm[(w * 4 + i) * NBLK + blockIdx.x];
    // ---- gather zin0 for 4 nodes: 8 neighbor-slots x 8 m per iteration + xor-butterfly
    float zin0v[4];
    #pragma unroll
    for (int i = 0; i < 4; ++i) {
        int n = nodes[i];
        int off = offs[n], dg = deg[n];
        float acc = (t < 8) ? x[n * 8 + t] : 0.f;
        for (int base = 0; base < dg; base += 8) {
            int k = base + g;
            float v = 0.f;
            if (k < dg) { int nb = esrc[off + k]; v = x[(size_t)nb * 8 + m]; }
            acc += v;
        }
        acc += __shfl_xor(acc, 8);
        acc += __shfl_xor(acc, 16);
        acc += __shfl_xor(acc, 32);   // all lanes: zin0[node i][m = t&7]
        zin0v[i] = acc;
    }
    // ---- h = relu(w10*zin0 + b1) built directly in B-frag layout
    bf16x8 bfr[2][2];
    #pragma unroll
    for (int q2 = 0; q2 < 2; ++q2) {
        int kb = q2 * 32 + (t >> 4) * 8;
        float4 wA = *(const float4*)&W10[kb];
        float4 wB = *(const float4*)&W10[kb + 4];
        float4 bA = *(const float4*)&B1[kb];
        float4 bB = *(const float4*)&B1[kb + 4];
        #pragma unroll
        for (int tau = 0; tau < 2; ++tau) {
            float zv = zin0v[tau * 2 + ((t & 15) >> 3)];
            U4B8 u;
            u.u.x = pack2(fmaxf(fmaf(wA.x, zv, bA.x), 0.f), fmaxf(fmaf(wA.y, zv, bA.y), 0.f));
            u.u.y = pack2(fmaxf(fmaf(wA.z, zv, bA.z), 0.f), fmaxf(fmaf(wA.w, zv, bA.w), 0.f));
            u.u.z = pack2(fmaxf(fmaf(wB.x, zv, bB.x), 0.f), fmaxf(fmaf(wB.y, zv, bB.y), 0.f));
            u.u.w = pack2(fmaxf(fmaf(wB.z, zv, bB.z), 0.f), fmaxf(fmaf(wB.w, zv, bB.w), 0.f));
            bfr[q2][tau] = u.b;
        }
    }
    // ---- linear2 via MFMA
    f32x4 acc[4][2];
    #pragma unroll
    for (int o4 = 0; o4 < 4; ++o4) {
        float4 bv = *(const float4*)&B2[o4 * 16 + (t >> 4) * 4];
        #pragma unroll
        for (int tau = 0; tau < 2; ++tau) acc[o4][tau] = (f32x4){bv.x, bv.y, bv.z, bv.w};
    }
    #pragma unroll
    for (int o4 = 0; o4 < 4; ++o4)
        #pragma unroll
        for (int q2 = 0; q2 < 2; ++q2) {
            U4B8 a; a.u = w2s[(o4 * 2 + q2) * 64 + t];
            #pragma unroll
            for (int tau = 0; tau < 2; ++tau)
                acc[o4][tau] = __builtin_amdgcn_mfma_f32_16x16x32_bf16(a.b, bfr[q2][tau], acc[o4][tau], 0, 0, 0);
        }
    #pragma unroll
    for (int o4 = 0; o4 < 4; ++o4)
        #pragma unroll
        for (int tau = 0; tau < 2; ++tau) {
            acc[o4][tau][0] = fmaxf(acc[o4][tau][0], 0.f);
            acc[o4][tau][1] = fmaxf(acc[o4][tau][1], 0.f);
            acc[o4][tau][2] = fmaxf(acc[o4][tau][2], 0.f);
            acc[o4][tau][3] = fmaxf(acc[o4][tau][3], 0.f);
        }
    // BN stats
    int sid = (blockIdx.x & (NSHADOW - 1)) * 128;
    #pragma unroll
    for (int o4 = 0; o4 < 4; ++o4)
        #pragma unroll
        for (int r = 0; r < 4; ++r) {
            float x0 = acc[o4][0][r], x1 = acc[o4][1][r];
            float sv = x0 + x1;
            float ssv = x0 * x0 + x1 * x1;
            sv += __shfl_xor(sv, 1);  ssv += __shfl_xor(ssv, 1);
            sv += __shfl_xor(sv, 2);  ssv += __shfl_xor(ssv, 2);
            sv += __shfl_xor(sv, 4);  ssv += __shfl_xor(ssv, 4);
            sv += __shfl_xor(sv, 8);  ssv += __shfl_xor(ssv, 8);
            if ((t & 15) == o4 * 4 + r) {
                int ch = o4 * 16 + (t >> 4) * 4 + r;
                atomicAdd(&shadow[sid + ch], sv);
                atomicAdd(&shadow[sid + 64 + ch], ssv);
            }
        }
    // pack z into zbuf, coalesced uint4 stores
    #pragma unroll
    for (int o4 = 0; o4 < 4; ++o4)
        #pragma unroll
        for (int tau = 0; tau < 2; ++tau) {
            uint* p = (uint*)&zbuf[(w * 32 + tau * 16 + (t & 15)) * ZSTRIDE + o4 * 16 + (t >> 4) * 4];
            p[0] = pack2(acc[o4][tau][0], acc[o4][tau][1]);
            p[1] = pack2(acc[o4][tau][2], acc[o4][tau][3]);
        }
    #pragma unroll
    for (int i = 0; i < 4; ++i) {
        uint4 pk = *(const uint4*)&zbuf[(w * 32 + i * 8 + (t >> 3)) * ZSTRIDE + (t & 7) * 8];
        ((uint4*)(zout + (size_t)nodes[i] * ROW))[t] = pk;
    }
}

// ---------------- fused layer (1..4): per-block BN finalize + bf16 gather (ILP2) + MFMA MLP (LDS weights)
__global__ __launch_bounds__(256) void k_layer(const ushort* __restrict__ zprev,
                                               const float* __restrict__ shadow_prev,
                                               const float* __restrict__ gammaP, const float* __restrict__ betaP,
                                               const int* __restrict__ offs, const int* __restrict__ deg,
                                               const int* __restrict__ esrc, const int* __restrict__ perm,
                                               const uint4* __restrict__ w1f, const float* __restrict__ B1,
                                               const uint4* __restrict__ w2f, const float* __restrict__ B2,
                                               ushort* __restrict__ zout, float* __restrict__ shadow) {
    __shared__ uint4 w1s[512];
    __shared__ uint4 w2s[512];
    __shared__ __align__(16) ushort zbuf[128 * ZSTRIDE];
    __shared__ float red[128];
    __shared__ __align__(16) float abl[128];
    int tid = threadIdx.x;
    // stage pre-packed weight A-frags into LDS (decouple lgkm from gather vmcnt)
    for (int s2 = tid; s2 < 512; s2 += 256) { w1s[s2] = w1f[s2]; w2s[s2] = w2f[s2]; }
    // per-block redundant BN finalize of previous layer
    if (tid < 128) {
        float s = 0.f;
        #pragma unroll
        for (int j = 0; j < NSHADOW; ++j) s += shadow_prev[j * 128 + tid];
        red[tid] = s;
    }
    __syncthreads();
    if (tid < 64) {
        float mean = red[tid] * (1.f / NM);
        float var = red[64 + tid] * (1.f / NM) - mean * mean;
        float a = gammaP[tid] * rsqrtf(var + 1e-5f);
        abl[tid] = a;
        abl[64 + tid] = betaP[tid] - mean * a;
    }
    __syncthreads();
    int w = tid >> 6, t = tid & 63;
    int nodes[4];
    #pragma unroll
    for (int i = 0; i < 4; ++i) nodes[i] = perm[(w * 4 + i) * NBLK + blockIdx.x];
    const float4* abp = (const float4*)abl;
    float4 Alo = abp[(t & 7) * 2], Ahi = abp[(t & 7) * 2 + 1];
    float4 Blo = abp[16 + (t & 7) * 2], Bhi = abp[16 + (t & 7) * 2 + 1];
    // ---- gather 4 nodes (wave-private), 2-way ILP, stage folded zin into zbuf
    for (int i = 0; i < 4; ++i) {
        int n = nodes[i];
        int off = offs[n], dg = deg[n];
        uint4 sv = ((const uint4*)(zprev + (size_t)n * ROW))[t];
        float a0 = bflo(sv.x), a1 = bfhi(sv.x), a2 = bflo(sv.y), a3 = bfhi(sv.y);
        float a4 = bflo(sv.z), a5 = bfhi(sv.z), a6 = bflo(sv.w), a7 = bfhi(sv.w);
        for (int base = 0; base < dg; base += 64) {
            int rem = dg - base;
            int cnt = rem < 64 ? rem : 64;
            int idx = (t < cnt) ? esrc[off + base + t] : 0;
            int j = 0;
            for (; j + 1 < cnt; j += 2) {
                int nb0 = __builtin_amdgcn_readlane(idx, j);
                int nb1 = __builtin_amdgcn_readlane(idx, j + 1);
                uint4 r0 = ((const uint4*)(zprev + (size_t)nb0 * ROW))[t];
                uint4 r1 = ((const uint4*)(zprev + (size_t)nb1 * ROW))[t];
                a0 += bflo(r0.x); a1 += bfhi(r0.x); a2 += bflo(r0.y); a3 += bfhi(r0.y);
                a4 += bflo(r0.z); a5 += bfhi(r0.z); a6 += bflo(r0.w); a7 += bfhi(r0.w);
                a0 += bflo(r1.x); a1 += bfhi(r1.x); a2 += bflo(r1.y); a3 += bfhi(r1.y);
                a4 += bflo(r1.z); a5 += bfhi(r1.z); a6 += bflo(r1.w); a7 += bfhi(r1.w);
            }
            if (j < cnt) {
                int nb = __builtin_amdgcn_readlane(idx, j);
                uint4 r = ((const uint4*)(zprev + (size_t)nb * ROW))[t];
                a0 += bflo(r.x); a1 += bfhi(r.x); a2 += bflo(r.y); a3 += bfhi(r.y);
                a4 += bflo(r.z); a5 += bfhi(r.z); a6 += bflo(r.w); a7 += bfhi(r.w);
            }
        }
        float dp1 = (float)(dg + 1);
        uint4 pk;
        pk.x = pack2(fmaf(Alo.x, a0, Blo.x * dp1), fmaf(Alo.y, a1, Blo.y * dp1));
        pk.y = pack2(fmaf(Alo.z, a2, Blo.z * dp1), fmaf(Alo.w, a3, Blo.w * dp1));
        pk.z = pack2(fmaf(Ahi.x, a4, Bhi.x * dp1), fmaf(Ahi.y, a5, Bhi.y * dp1));
        pk.w = pack2(fmaf(Ahi.z, a6, Bhi.z * dp1), fmaf(Ahi.w, a7, Bhi.w * dp1));
        *(uint4*)&zbuf[(w * 32 + i * 8 + (t >> 3)) * ZSTRIDE + (t & 7) * 8] = pk;
    }
    // ---- MLP via MFMA: D[64 o x 32 nm] per wave; weights from LDS
    bf16x8 bfr[2][2];
    #pragma unroll
    for (int tau = 0; tau < 2; ++tau)
        #pragma unroll
        for (int q2 = 0; q2 < 2; ++q2) {
            U4B8 u;
            u.u = *(const uint4*)&zbuf[(w * 32 + tau * 16 + (t & 15)) * ZSTRIDE + q2 * 32 + (t >> 4) * 8];
            bfr[q2][tau] = u.b;
        }
    f32x4 acc[4][2];
    #pragma unroll
    for (int o4 = 0; o4 < 4; ++o4) {
        float4 bv = *(const float4*)&B1[o4 * 16 + (t >> 4) * 4];
        #pragma unroll
        for (int tau = 0; tau < 2; ++tau) acc[o4][tau] = (f32x4){bv.x, bv.y, bv.z, bv.w};
    }
    #pragma unroll
    for (int o4 = 0; o4 < 4; ++o4)
        #pragma unroll
        for (int q2 = 0; q2 < 2; ++q2) {
            U4B8 a; a.u = w1s[(o4 * 2 + q2) * 64 + t];
            #pragma unroll
            for (int tau = 0; tau < 2; ++tau)
                acc[o4][tau] = __builtin_amdgcn_mfma_f32_16x16x32_bf16(a.b, bfr[q2][tau], acc[o4][tau], 0, 0, 0);
        }
    #pragma unroll
    for (int o4 = 0; o4 < 4; ++o4)
        #pragma unroll
        for (int tau = 0; tau < 2; ++tau) {
            f32x4 v = acc[o4][tau];
            float h0 = fmaxf(v[0], 0.f), h1 = fmaxf(v[1], 0.f), h2 = fmaxf(v[2], 0.f), h3 = fmaxf(v[3], 0.f);
            uint* p = (uint*)&zbuf[(w * 32 + tau * 16 + (t & 15)) * ZSTRIDE + o4 * 16 + (t >> 4) * 4];
            p[0] = pack2(h0, h1); p[1] = pack2(h2, h3);
        }
    #pragma unroll
    for (int tau = 0; tau < 2; ++tau)
        #pragma unroll
        for (int q2 = 0; q2 < 2; ++q2) {
            U4B8 u;
            u.u = *(const uint4*)&zbuf[(w * 32 + tau * 16 + (t & 15)) * ZSTRIDE + q2 * 32 + (t >> 4) * 8];
            bfr[q2][tau] = u.b;
        }
    #pragma unroll
    for (int o4 = 0; o4 < 4; ++o4) {
        float4 bv = *(const float4*)&B2[o4 * 16 + (t >> 4) * 4];
        #pragma unroll
        for (int tau = 0; tau < 2; ++tau) acc[o4][tau] = (f32x4){bv.x, bv.y, bv.z, bv.w};
    }
    #pragma unroll
    for (int o4 = 0; o4 < 4; ++o4)
        #pragma unroll
        for (int q2 = 0; q2 < 2; ++q2) {
            U4B8 a; a.u = w2s[(o4 * 2 + q2) * 64 + t];
            #pragma unroll
            for (int tau = 0; tau < 2; ++tau)
                acc[o4][tau] = __builtin_amdgcn_mfma_f32_16x16x32_bf16(a.b, bfr[q2][tau], acc[o4][tau], 0, 0, 0);
        }
    #pragma unroll
    for (int o4 = 0; o4 < 4; ++o4)
        #pragma unroll
        for (int tau = 0; tau < 2; ++tau) {
            acc[o4][tau][0] = fmaxf(acc[o4][tau][0], 0.f);
            acc[o4][tau][1] = fmaxf(acc[o4][tau][1], 0.f);
            acc[o4][tau][2] = fmaxf(acc[o4][tau][2], 0.f);
            acc[o4][tau][3] = fmaxf(acc[o4][tau][3], 0.f);
        }
    // BN stats: butterfly over 16-lane column group, 2 predicated atomics per matching lane
    int sid = (blockIdx.x & (NSHADOW - 1)) * 128;
    #pragma unroll
    for (int o4 = 0; o4 < 4; ++o4)
        #pragma unroll
        for (int r = 0; r < 4; ++r) {
            float x0 = acc[o4][0][r], x1 = acc[o4][1][r];
            float sv = x0 + x1;
            float ssv = x0 * x0 + x1 * x1;
            sv += __shfl_xor(sv, 1);  ssv += __shfl_xor(ssv, 1);
            sv += __shfl_xor(sv, 2);  ssv += __shfl_xor(ssv, 2);
            sv += __shfl_xor(sv, 4);  ssv += __shfl_xor(ssv, 4);
            sv += __shfl_xor(sv, 8);  ssv += __shfl_xor(ssv, 8);
            if ((t & 15) == o4 * 4 + r) {
                int ch = o4 * 16 + (t >> 4) * 4 + r;
                atomicAdd(&shadow[sid + ch], sv);
                atomicAdd(&shadow[sid + 64 + ch], ssv);
            }
        }
    // pack z2 into zbuf, then coalesced uint4 stores per node
    #pragma unroll
    for (int o4 = 0; o4 < 4; ++o4)
        #pragma unroll
        for (int tau = 0; tau < 2; ++tau) {
            uint* p = (uint*)&zbuf[(w * 32 + tau * 16 + (t & 15)) * ZSTRIDE + o4 * 16 + (t >> 4) * 4];
            p[0] = pack2(acc[o4][tau][0], acc[o4][tau][1]);
            p[1] = pack2(acc[o4][tau][2], acc[o4][tau][3]);
        }
    #pragma unroll
    for (int i = 0; i < 4; ++i) {
        uint4 pk = *(const uint4*)&zbuf[(w * 32 + i * 8 + (t >> 3)) * ZSTRIDE + (t & 7) * 8];
        ((uint4*)(zout + (size_t)nodes[i] * ROW))[t] = pk;
    }
}

// ---------------- pooling over nodes (bf16 raw z, [n][m][c] rows)
__global__ __launch_bounds__(256) void k_pool(const uint* __restrict__ z2, float* __restrict__ pool) {
    int t = blockIdx.x * 256 + threadIdx.x;            // 65536 threads
    float s0 = 0.f, s1 = 0.f;
    for (int u = t; u < N_NODES * ROW / 2; u += 65536) {
        uint v = z2[u];
        s0 += bflo(v); s1 += bfhi(v);
    }
    int k2 = t & 255;                                   // uint index within a row; position = m*64+c
    atomicAdd(&pool[k2 * 2], s0);
    atomicAdd(&pool[k2 * 2 + 1], s1);
}

// ---------------- head: fold layer-4 BN finalize + pool-normalize + linear + sigmoid
__global__ __launch_bounds__(64) void k_out(const float* __restrict__ pool, const float* __restrict__ shadow4,
                                            const float* __restrict__ gamma4, const float* __restrict__ beta4,
                                            const float* __restrict__ wout, const float* __restrict__ bout,
                                            float* __restrict__ out) {
    int c = threadIdx.x;
    float s = 0.f, ss = 0.f;
    #pragma unroll
    for (int j = 0; j < NSHADOW; ++j) { s += shadow4[j * 128 + c]; ss += shadow4[j * 128 + 64 + c]; }
    float mean = s * (1.f / NM);
    float var = ss * (1.f / NM) - mean * mean;
    float a = gamma4[c] * rsqrtf(var + 1e-5f);
    float b = beta4[c] - mean * a;
    float wv = wout[c];
    for (int m = 0; m < 8; ++m) {
        float v = wv * (a * pool[m * 64 + c] * (1.f / N_NODES) + b);
        for (int off = 32; off > 0; off >>= 1) v += __shfl_down(v, off);
        if (c == 0) out[m] = 1.f / (1.f + expf(-(v + bout[0])));
    }
}

extern "C" void kernel_launch(void* const* d_in, const int* in_sizes, int n_in,
                              void* d_out, int out_size, void* d_ws, size_t ws_size,
                              hipStream_t stream) {
    const float* x     = (const float*)d_in[0];
    const int*   ei    = (const int*)d_in[1];
    const int*   srcp  = ei;
    const int*   dstp  = ei + N_EDGES;
    const float* w1_0  = (const float*)d_in[3];
    const float* w1    = (const float*)d_in[4];   // [4][64][64]
    const float* b1    = (const float*)d_in[5];   // [5][64]
    const float* w2    = (const float*)d_in[6];   // [5][64][64]
    const float* b2    = (const float*)d_in[7];
    const float* gamma = (const float*)d_in[8];
    const float* beta  = (const float*)d_in[9];
    const float* wout  = (const float*)d_in[10];
    const float* bout  = (const float*)d_in[11];
    float* out = (float*)d_out;

    char* ws = (char*)d_ws;
    size_t off = 0;
    auto alloc = [&](size_t bytes) -> void* {
        void* p = ws + off;
        off = (off + bytes + 255) & ~(size_t)255;
        return p;
    };
    ushort* zA   = (ushort*)alloc((size_t)N_NODES * ROW * 2);   // 20.5 MB bf16
    ushort* zB   = (ushort*)alloc((size_t)N_NODES * ROW * 2);   // 20.5 MB bf16
    uint4* wfrag = (uint4*)alloc(4608 * 16);                    // pre-packed A-fragments
    // ---- contiguous zero-initialized span: deg, cursor, shadow[5], pool, bins
    int* deg      = (int*)alloc(N_NODES * 4);
    int* cursor   = (int*)alloc(N_NODES * 4);
    float* shadow = (float*)alloc(5 * NSHADOW * 128 * 4);
    float* pool   = (float*)alloc(512 * 4);
    int* bins     = (int*)alloc(64 * 4);
    size_t zero_bytes = (size_t)((char*)bins - (char*)deg) + 64 * 4;
    // ---- uninitialized scratch
    int* bincur   = (int*)alloc(64 * 4);
    int* perm     = (int*)alloc(N_NODES * 4);
    int* offs     = (int*)alloc(N_NODES * 4);
    int* esrc     = (int*)alloc(N_EDGES * 4);
    int* csum     = (int*)alloc(NCHUNK * 4);
    int* chunkoff = (int*)alloc(NCHUNK * 4);

    hipMemsetAsync(deg, 0, zero_bytes, stream);

    // CSR build + degree-balanced perm + weight pre-pack
    k_hist<<<(N_EDGES + 255) / 256, 256, 0, stream>>>(dstp, deg);
    k_csum<<<NCHUNK, 256, 0, stream>>>(deg, csum);
    k_cscan<<<1, 128, 0, stream>>>(csum, chunkoff);
    k_chunkscan<<<NCHUNK, 256, 0, stream>>>(deg, chunkoff, offs);
    k_fill<<<(N_EDGES + 255) / 256, 256, 0, stream>>>(srcp, dstp, offs, cursor, esrc);
    k_dhist<<<NCHUNK, 256, 0, stream>>>(deg, bins);
    k_dscan<<<1, 64, 0, stream>>>(bins, bincur);
    k_dscatter<<<NCHUNK, 256, 0, stream>>>(deg, bincur, perm);
    k_prep<<<18, 256, 0, stream>>>(w1, w2, wfrag);

    // layer 0 (MFMA)
    k_layer0<<<NBLK, 256, 0, stream>>>(x, offs, deg, esrc, perm, w1_0, b1, wfrag + 4096, b2, zA, shadow);

    // layers 1..4 fused (per-block BN finalize of prev layer); ping-pong zA<->zB
    const ushort* zin = zA;
    ushort* zo = zB;
    for (int i = 1; i <= 4; ++i) {
        k_layer<<<NBLK, 256, 0, stream>>>(zin,
                                          shadow + (size_t)(i - 1) * NSHADOW * 128,
                                          gamma + (i - 1) * 64, beta + (i - 1) * 64,
                                          offs, deg, esrc, perm,
                                          wfrag + (size_t)(i - 1) * 1024, b1 + i * 64,
                                          wfrag + (size_t)(i - 1) * 1024 + 512, b2 + i * 64,
                                          (ushort*)zo,
                                          shadow + (size_t)i * NSHADOW * 128);
        const ushort* tmp = zin; zin = zo; zo = (ushort*)tmp;
    }
    // after 4 swaps, final raw z (layer 4) is back in zA

    // head
    k_pool<<<256, 256, 0, stream>>>((const uint*)zA, pool);
    k_out<<<1, 64, 0, stream>>>(pool, shadow + 4 * NSHADOW * 128, gamma + 256, beta + 256, wout, bout, out);
}

// Round 10
// 483.011 us; speedup vs baseline: 1.2177x; 1.2177x over previous
//
#include <hip/hip_runtime.h>

#define N_NODES 20000
#define N_EDGES 320000
#define HID 64
#define MDIM 8
#define ROW 512            // HID*MDIM elements per node row (layout: [n][m][c])
#define NM 160000.0f       // N_NODES*MDIM
#define NCHUNK 79          // ceil(20000/256)
#define NSHADOW 16         // shadow copies per layer
#define ZSTRIDE 72         // shorts per nm-row (64 + 8 pad)

typedef unsigned int uint;
typedef unsigned char uchar;
typedef unsigned short ushort;
typedef __attribute__((ext_vector_type(8))) short bf16x8;
typedef __attribute__((ext_vector_type(4))) float f32x4;
typedef __attribute__((ext_vector_type(2))) float f32x2;

union U4B8 { uint4 u; bf16x8 b; };

__device__ __forceinline__ float bflo(uint u) { return __uint_as_float(u << 16); }
__device__ __forceinline__ float bfhi(uint u) { return __uint_as_float(u & 0xffff0000u); }
__device__ __forceinline__ uint f2bf(float f) {   // round-to-nearest-even
    uint u = __float_as_uint(f);
    return (u + 0x7fffu + ((u >> 16) & 1u)) >> 16;
}
__device__ __forceinline__ uint pack2(float lo, float hi) { return f2bf(lo) | (f2bf(hi) << 16); }
// pack 8 floats (from a bf16x8-packed uint4) into 8 fp8-e4m3 bytes
__device__ __forceinline__ uint2 pkfp8(uint4 pk) {
    int lo = 0, hi = 0;
    lo = __builtin_amdgcn_cvt_pk_fp8_f32(bflo(pk.x), bfhi(pk.x), lo, false);
    lo = __builtin_amdgcn_cvt_pk_fp8_f32(bflo(pk.y), bfhi(pk.y), lo, true);
    hi = __builtin_amdgcn_cvt_pk_fp8_f32(bflo(pk.z), bfhi(pk.z), hi, false);
    hi = __builtin_amdgcn_cvt_pk_fp8_f32(bflo(pk.w), bfhi(pk.w), hi, true);
    uint2 r; r.x = (uint)lo; r.y = (uint)hi; return r;
}

// ---------------- CSR build ----------------
__global__ __launch_bounds__(256) void k_hist(const int* __restrict__ dst, int* __restrict__ deg) {
    int e = blockIdx.x * 256 + threadIdx.x;
    if (e < N_EDGES) atomicAdd(&deg[dst[e]], 1);
}

__global__ __launch_bounds__(256) void k_csum(const int* __restrict__ deg, int* __restrict__ csum) {
    __shared__ int r[256];
    int t = threadIdx.x, i = blockIdx.x * 256 + t;
    r[t] = (i < N_NODES) ? deg[i] : 0;
    __syncthreads();
    for (int s = 128; s > 0; s >>= 1) { if (t < s) r[t] += r[t + s]; __syncthreads(); }
    if (t == 0) csum[blockIdx.x] = r[0];
}

__global__ __launch_bounds__(128) void k_cscan(const int* __restrict__ csum, int* __restrict__ chunkoff) {
    __shared__ int s[128];
    int t = threadIdx.x;
    s[t] = (t < NCHUNK) ? csum[t] : 0;
    __syncthreads();
    if (t == 0) { int run = 0; for (int j = 0; j < NCHUNK; ++j) { int x = s[j]; s[j] = run; run += x; } }
    __syncthreads();
    if (t < NCHUNK) chunkoff[t] = s[t];
}

__global__ __launch_bounds__(256) void k_chunkscan(const int* __restrict__ deg, const int* __restrict__ chunkoff,
                                                   int* __restrict__ offs) {
    __shared__ int sd[256];
    int t = threadIdx.x, i = blockIdx.x * 256 + t;
    int v = (i < N_NODES) ? deg[i] : 0;
    sd[t] = v;
    __syncthreads();
    for (int off = 1; off < 256; off <<= 1) {
        int x = (t >= off) ? sd[t - off] : 0;
        __syncthreads();
        sd[t] += x;
        __syncthreads();
    }
    if (i < N_NODES) offs[i] = sd[t] - v + chunkoff[blockIdx.x];
}

__global__ __launch_bounds__(256) void k_fill(const int* __restrict__ src, const int* __restrict__ dst,
                                              const int* __restrict__ offs, int* __restrict__ cursor,
                                              int* __restrict__ esrc) {
    int e = blockIdx.x * 256 + threadIdx.x;
    if (e < N_EDGES) {
        int d = dst[e];
        int p = atomicAdd(&cursor[d], 1);
        esrc[offs[d] + p] = src[e];
    }
}

// ---------------- pre-pack weights into MFMA A-fragment order (bf16)
// slots 0..4095: layers 1..4, {w1,w2} x 512 ; slots 4096..4607: layer-0 w2
__global__ __launch_bounds__(256) void k_prep(const float* __restrict__ w1, const float* __restrict__ w2,
                                              uint4* __restrict__ wfrag) {
    int id = blockIdx.x * 256 + threadIdx.x;   // 4608 total
    if (id >= 4608) return;
    const float* W;
    int s;
    if (id < 4096) {
        int layer = id >> 10;          // 0..3 -> model layer layer+1
        int rem = id & 1023;
        int which = rem >> 9;          // 0: w1, 1: w2
        s = rem & 511;
        W = which ? &w2[(size_t)(layer + 1) * 4096] : &w1[(size_t)layer * 4096];
    } else {
        s = id - 4096;
        W = w2;                        // layer-0 w2
    }
    int f = s >> 6, l = s & 63;
    int o = (f >> 1) * 16 + (l & 15);
    int c0 = (f & 1) * 32 + (l >> 4) * 8;
    const float* p = &W[o * 64 + c0];
    uint4 a;
    a.x = pack2(p[0], p[1]); a.y = pack2(p[2], p[3]);
    a.z = pack2(p[4], p[5]); a.w = pack2(p[6], p[7]);
    wfrag[id] = a;
}

// ---------------- fused layer 0 (MFMA): gather x (C=1) + rank-1 linear1 in B-frag regs + MFMA linear2
// block = 4 waves x 4 nodes; writes bf16 + fp8 copies
__global__ __launch_bounds__(256) void k_layer0(const float* __restrict__ x, const int* __restrict__ offs,
                                                const int* __restrict__ deg, const int* __restrict__ esrc,
                                                const float* __restrict__ W10, const float* __restrict__ B1,
                                                const uint4* __restrict__ w2f0, const float* __restrict__ B2,
                                                ushort* __restrict__ zout, uchar* __restrict__ zout8,
                                                float* __restrict__ shadow) {
    __shared__ uint4 w2s[512];
    __shared__ __align__(16) ushort zbuf[128 * ZSTRIDE];
    int tid = threadIdx.x;
    for (int s2 = tid; s2 < 512; s2 += 256) w2s[s2] = w2f0[s2];
    __syncthreads();
    int w = tid >> 6, t = tid & 63;
    int n0 = blockIdx.x * 16 + w * 4;
    int g = t >> 3, m = t & 7;
    // ---- gather zin0 for 4 nodes: 8 neighbor-slots x 8 m per iteration + xor-butterfly
    float zin0v[4];
    #pragma unroll
    for (int i = 0; i < 4; ++i) {
        int n = n0 + i;
        int off = offs[n], dg = deg[n];
        float acc = (t < 8) ? x[n * 8 + t] : 0.f;
        for (int base = 0; base < dg; base += 8) {
            int k = base + g;
            float v = 0.f;
            if (k < dg) { int nb = esrc[off + k]; v = x[(size_t)nb * 8 + m]; }
            acc += v;
        }
        acc += __shfl_xor(acc, 8);
        acc += __shfl_xor(acc, 16);
        acc += __shfl_xor(acc, 32);   // all lanes: zin0[node i][m = t&7]
        zin0v[i] = acc;
    }
    // ---- h = relu(w10*zin0 + b1) built directly in B-frag layout
    bf16x8 bfr[2][2];
    #pragma unroll
    for (int q2 = 0; q2 < 2; ++q2) {
        int kb = q2 * 32 + (t >> 4) * 8;
        float4 wA = *(const float4*)&W10[kb];
        float4 wB = *(const float4*)&W10[kb + 4];
        float4 bA = *(const float4*)&B1[kb];
        float4 bB = *(const float4*)&B1[kb + 4];
        #pragma unroll
        for (int tau = 0; tau < 2; ++tau) {
            float zv = zin0v[tau * 2 + ((t & 15) >> 3)];
            U4B8 u;
            u.u.x = pack2(fmaxf(fmaf(wA.x, zv, bA.x), 0.f), fmaxf(fmaf(wA.y, zv, bA.y), 0.f));
            u.u.y = pack2(fmaxf(fmaf(wA.z, zv, bA.z), 0.f), fmaxf(fmaf(wA.w, zv, bA.w), 0.f));
            u.u.z = pack2(fmaxf(fmaf(wB.x, zv, bB.x), 0.f), fmaxf(fmaf(wB.y, zv, bB.y), 0.f));
            u.u.w = pack2(fmaxf(fmaf(wB.z, zv, bB.z), 0.f), fmaxf(fmaf(wB.w, zv, bB.w), 0.f));
            bfr[q2][tau] = u.b;
        }
    }
    // ---- linear2 via MFMA
    f32x4 acc[4][2];
    #pragma unroll
    for (int o4 = 0; o4 < 4; ++o4) {
        float4 bv = *(const float4*)&B2[o4 * 16 + (t >> 4) * 4];
        #pragma unroll
        for (int tau = 0; tau < 2; ++tau) acc[o4][tau] = (f32x4){bv.x, bv.y, bv.z, bv.w};
    }
    #pragma unroll
    for (int o4 = 0; o4 < 4; ++o4)
        #pragma unroll
        for (int q2 = 0; q2 < 2; ++q2) {
            U4B8 a; a.u = w2s[(o4 * 2 + q2) * 64 + t];
            #pragma unroll
            for (int tau = 0; tau < 2; ++tau)
                acc[o4][tau] = __builtin_amdgcn_mfma_f32_16x16x32_bf16(a.b, bfr[q2][tau], acc[o4][tau], 0, 0, 0);
        }
    #pragma unroll
    for (int o4 = 0; o4 < 4; ++o4)
        #pragma unroll
        for (int tau = 0; tau < 2; ++tau) {
            acc[o4][tau][0] = fmaxf(acc[o4][tau][0], 0.f);
            acc[o4][tau][1] = fmaxf(acc[o4][tau][1], 0.f);
            acc[o4][tau][2] = fmaxf(acc[o4][tau][2], 0.f);
            acc[o4][tau][3] = fmaxf(acc[o4][tau][3], 0.f);
        }
    // BN stats
    int sid = (blockIdx.x & (NSHADOW - 1)) * 128;
    #pragma unroll
    for (int o4 = 0; o4 < 4; ++o4)
        #pragma unroll
        for (int r = 0; r < 4; ++r) {
            float x0 = acc[o4][0][r], x1 = acc[o4][1][r];
            float sv = x0 + x1;
            float ssv = x0 * x0 + x1 * x1;
            sv += __shfl_xor(sv, 1);  ssv += __shfl_xor(ssv, 1);
            sv += __shfl_xor(sv, 2);  ssv += __shfl_xor(ssv, 2);
            sv += __shfl_xor(sv, 4);  ssv += __shfl_xor(ssv, 4);
            sv += __shfl_xor(sv, 8);  ssv += __shfl_xor(ssv, 8);
            if ((t & 15) == o4 * 4 + r) {
                int ch = o4 * 16 + (t >> 4) * 4 + r;
                atomicAdd(&shadow[sid + ch], sv);
                atomicAdd(&shadow[sid + 64 + ch], ssv);
            }
        }
    // pack z into zbuf, coalesced uint4 (bf16) + uint2 (fp8) stores
    #pragma unroll
    for (int o4 = 0; o4 < 4; ++o4)
        #pragma unroll
        for (int tau = 0; tau < 2; ++tau) {
            uint* p = (uint*)&zbuf[(w * 32 + tau * 16 + (t & 15)) * ZSTRIDE + o4 * 16 + (t >> 4) * 4];
            p[0] = pack2(acc[o4][tau][0], acc[o4][tau][1]);
            p[1] = pack2(acc[o4][tau][2], acc[o4][tau][3]);
        }
    #pragma unroll
    for (int i = 0; i < 4; ++i) {
        uint4 pk = *(const uint4*)&zbuf[(w * 32 + i * 8 + (t >> 3)) * ZSTRIDE + (t & 7) * 8];
        ((uint4*)(zout + (size_t)(n0 + i) * ROW))[t] = pk;
        ((uint2*)(zout8 + (size_t)(n0 + i) * ROW))[t] = pkfp8(pk);
    }
}

// ---------------- fused layer (1..4): per-block BN finalize + fp8 gather (ILP2) + MFMA MLP (LDS weights)
__global__ __launch_bounds__(256) void k_layer(const ushort* __restrict__ zprev,
                                               const uchar* __restrict__ zprev8,
                                               const float* __restrict__ shadow_prev,
                                               const float* __restrict__ gammaP, const float* __restrict__ betaP,
                                               const int* __restrict__ offs, const int* __restrict__ deg,
                                               const int* __restrict__ esrc,
                                               const uint4* __restrict__ w1f, const float* __restrict__ B1,
                                               const uint4* __restrict__ w2f, const float* __restrict__ B2,
                                               ushort* __restrict__ zout, uchar* __restrict__ zout8,
                                               float* __restrict__ shadow) {
    __shared__ uint4 w1s[512];
    __shared__ uint4 w2s[512];
    __shared__ __align__(16) ushort zbuf[128 * ZSTRIDE];
    __shared__ float red[128];
    __shared__ __align__(16) float abl[128];
    int tid = threadIdx.x;
    // stage pre-packed weight A-frags into LDS (decouple lgkm from gather vmcnt)
    for (int s2 = tid; s2 < 512; s2 += 256) { w1s[s2] = w1f[s2]; w2s[s2] = w2f[s2]; }
    // per-block redundant BN finalize of previous layer
    if (tid < 128) {
        float s = 0.f;
        #pragma unroll
        for (int j = 0; j < NSHADOW; ++j) s += shadow_prev[j * 128 + tid];
        red[tid] = s;
    }
    __syncthreads();
    if (tid < 64) {
        float mean = red[tid] * (1.f / NM);
        float var = red[64 + tid] * (1.f / NM) - mean * mean;
        float a = gammaP[tid] * rsqrtf(var + 1e-5f);
        abl[tid] = a;
        abl[64 + tid] = betaP[tid] - mean * a;
    }
    __syncthreads();
    int w = tid >> 6, t = tid & 63;
    int n0 = blockIdx.x * 16 + w * 4;
    const float4* abp = (const float4*)abl;
    float4 Alo = abp[(t & 7) * 2], Ahi = abp[(t & 7) * 2 + 1];
    float4 Blo = abp[16 + (t & 7) * 2], Bhi = abp[16 + (t & 7) * 2 + 1];
    // ---- gather 4 nodes (wave-private): self from bf16, neighbors from fp8, 2-way ILP
    for (int i = 0; i < 4; ++i) {
        int n = n0 + i;
        int off = offs[n], dg = deg[n];
        uint4 sv = ((const uint4*)(zprev + (size_t)n * ROW))[t];
        float a0 = bflo(sv.x), a1 = bfhi(sv.x), a2 = bflo(sv.y), a3 = bfhi(sv.y);
        float a4 = bflo(sv.z), a5 = bfhi(sv.z), a6 = bflo(sv.w), a7 = bfhi(sv.w);
        for (int base = 0; base < dg; base += 64) {
            int rem = dg - base;
            int cnt = rem < 64 ? rem : 64;
            int idx = (t < cnt) ? esrc[off + base + t] : 0;
            int j = 0;
            for (; j + 1 < cnt; j += 2) {
                int nb0 = __builtin_amdgcn_readlane(idx, j);
                int nb1 = __builtin_amdgcn_readlane(idx, j + 1);
                uint2 r0 = ((const uint2*)(zprev8 + (size_t)nb0 * ROW))[t];
                uint2 r1 = ((const uint2*)(zprev8 + (size_t)nb1 * ROW))[t];
                f32x2 p0 = __builtin_amdgcn_cvt_pk_f32_fp8((int)r0.x, false);
                f32x2 p1 = __builtin_amdgcn_cvt_pk_f32_fp8((int)r0.x, true);
                f32x2 p2 = __builtin_amdgcn_cvt_pk_f32_fp8((int)r0.y, false);
                f32x2 p3 = __builtin_amdgcn_cvt_pk_f32_fp8((int)r0.y, true);
                a0 += p0.x; a1 += p0.y; a2 += p1.x; a3 += p1.y;
                a4 += p2.x; a5 += p2.y; a6 += p3.x; a7 += p3.y;
                f32x2 q0 = __builtin_amdgcn_cvt_pk_f32_fp8((int)r1.x, false);
                f32x2 q1 = __builtin_amdgcn_cvt_pk_f32_fp8((int)r1.x, true);
                f32x2 q2 = __builtin_amdgcn_cvt_pk_f32_fp8((int)r1.y, false);
                f32x2 q3 = __builtin_amdgcn_cvt_pk_f32_fp8((int)r1.y, true);
                a0 += q0.x; a1 += q0.y; a2 += q1.x; a3 += q1.y;
                a4 += q2.x; a5 += q2.y; a6 += q3.x; a7 += q3.y;
            }
            if (j < cnt) {
                int nb = __builtin_amdgcn_readlane(idx, j);
                uint2 r = ((const uint2*)(zprev8 + (size_t)nb * ROW))[t];
                f32x2 p0 = __builtin_amdgcn_cvt_pk_f32_fp8((int)r.x, false);
                f32x2 p1 = __builtin_amdgcn_cvt_pk_f32_fp8((int)r.x, true);
                f32x2 p2 = __builtin_amdgcn_cvt_pk_f32_fp8((int)r.y, false);
                f32x2 p3 = __builtin_amdgcn_cvt_pk_f32_fp8((int)r.y, true);
                a0 += p0.x; a1 += p0.y; a2 += p1.x; a3 += p1.y;
                a4 += p2.x; a5 += p2.y; a6 += p3.x; a7 += p3.y;
            }
        }
        float dp1 = (float)(dg + 1);
        uint4 pk;
        pk.x = pack2(fmaf(Alo.x, a0, Blo.x * dp1), fmaf(Alo.y, a1, Blo.y * dp1));
        pk.y = pack2(fmaf(Alo.z, a2, Blo.z * dp1), fmaf(Alo.w, a3, Blo.w * dp1));
        pk.z = pack2(fmaf(Ahi.x, a4, Bhi.x * dp1), fmaf(Ahi.y, a5, Bhi.y * dp1));
        pk.w = pack2(fmaf(Ahi.z, a6, Bhi.z * dp1), fmaf(Ahi.w, a7, Bhi.w * dp1));
        *(uint4*)&zbuf[(w * 32 + i * 8 + (t >> 3)) * ZSTRIDE + (t & 7) * 8] = pk;
    }
    // ---- MLP via MFMA: D[64 o x 32 nm] per wave; weights from LDS
    bf16x8 bfr[2][2];
    #pragma unroll
    for (int tau = 0; tau < 2; ++tau)
        #pragma unroll
        for (int q2 = 0; q2 < 2; ++q2) {
            U4B8 u;
            u.u = *(const uint4*)&zbuf[(w * 32 + tau * 16 + (t & 15)) * ZSTRIDE + q2 * 32 + (t >> 4) * 8];
            bfr[q2][tau] = u.b;
        }
    f32x4 acc[4][2];
    #pragma unroll
    for (int o4 = 0; o4 < 4; ++o4) {
        float4 bv = *(const float4*)&B1[o4 * 16 + (t >> 4) * 4];
        #pragma unroll
        for (int tau = 0; tau < 2; ++tau) acc[o4][tau] = (f32x4){bv.x, bv.y, bv.z, bv.w};
    }
    #pragma unroll
    for (int o4 = 0; o4 < 4; ++o4)
        #pragma unroll
        for (int q2 = 0; q2 < 2; ++q2) {
            U4B8 a; a.u = w1s[(o4 * 2 + q2) * 64 + t];
            #pragma unroll
            for (int tau = 0; tau < 2; ++tau)
                acc[o4][tau] = __builtin_amdgcn_mfma_f32_16x16x32_bf16(a.b, bfr[q2][tau], acc[o4][tau], 0, 0, 0);
        }
    #pragma unroll
    for (int o4 = 0; o4 < 4; ++o4)
        #pragma unroll
        for (int tau = 0; tau < 2; ++tau) {
            f32x4 v = acc[o4][tau];
            float h0 = fmaxf(v[0], 0.f), h1 = fmaxf(v[1], 0.f), h2 = fmaxf(v[2], 0.f), h3 = fmaxf(v[3], 0.f);
            uint* p = (uint*)&zbuf[(w * 32 + tau * 16 + (t & 15)) * ZSTRIDE + o4 * 16 + (t >> 4) * 4];
            p[0] = pack2(h0, h1); p[1] = pack2(h2, h3);
        }
    #pragma unroll
    for (int tau = 0; tau < 2; ++tau)
        #pragma unroll
        for (int q2 = 0; q2 < 2; ++q2) {
            U4B8 u;
            u.u = *(const uint4*)&zbuf[(w * 32 + tau * 16 + (t & 15)) * ZSTRIDE + q2 * 32 + (t >> 4) * 8];
            bfr[q2][tau] = u.b;
        }
    #pragma unroll
    for (int o4 = 0; o4 < 4; ++o4) {
        float4 bv = *(const float4*)&B2[o4 * 16 + (t >> 4) * 4];
        #pragma unroll
        for (int tau = 0; tau < 2; ++tau) acc[o4][tau] = (f32x4){bv.x, bv.y, bv.z, bv.w};
    }
    #pragma unroll
    for (int o4 = 0; o4 < 4; ++o4)
        #pragma unroll
        for (int q2 = 0; q2 < 2; ++q2) {
            U4B8 a; a.u = w2s[(o4 * 2 + q2) * 64 + t];
            #pragma unroll
            for (int tau = 0; tau < 2; ++tau)
                acc[o4][tau] = __builtin_amdgcn_mfma_f32_16x16x32_bf16(a.b, bfr[q2][tau], acc[o4][tau], 0, 0, 0);
        }
    #pragma unroll
    for (int o4 = 0; o4 < 4; ++o4)
        #pragma unroll
        for (int tau = 0; tau < 2; ++tau) {
            acc[o4][tau][0] = fmaxf(acc[o4][tau][0], 0.f);
            acc[o4][tau][1] = fmaxf(acc[o4][tau][1], 0.f);
            acc[o4][tau][2] = fmaxf(acc[o4][tau][2], 0.f);
            acc[o4][tau][3] = fmaxf(acc[o4][tau][3], 0.f);
        }
    // BN stats: butterfly over 16-lane column group, 2 predicated atomics per matching lane
    int sid = (blockIdx.x & (NSHADOW - 1)) * 128;
    #pragma unroll
    for (int o4 = 0; o4 < 4; ++o4)
        #pragma unroll
        for (int r = 0; r < 4; ++r) {
            float x0 = acc[o4][0][r], x1 = acc[o4][1][r];
            float sv = x0 + x1;
            float ssv = x0 * x0 + x1 * x1;
            sv += __shfl_xor(sv, 1);  ssv += __shfl_xor(ssv, 1);
            sv += __shfl_xor(sv, 2);  ssv += __shfl_xor(ssv, 2);
            sv += __shfl_xor(sv, 4);  ssv += __shfl_xor(ssv, 4);
            sv += __shfl_xor(sv, 8);  ssv += __shfl_xor(ssv, 8);
            if ((t & 15) == o4 * 4 + r) {
                int ch = o4 * 16 + (t >> 4) * 4 + r;
                atomicAdd(&shadow[sid + ch], sv);
                atomicAdd(&shadow[sid + 64 + ch], ssv);
            }
        }
    // pack z2 into zbuf, then coalesced bf16 + fp8 stores per node
    #pragma unroll
    for (int o4 = 0; o4 < 4; ++o4)
        #pragma unroll
        for (int tau = 0; tau < 2; ++tau) {
            uint* p = (uint*)&zbuf[(w * 32 + tau * 16 + (t & 15)) * ZSTRIDE + o4 * 16 + (t >> 4) * 4];
            p[0] = pack2(acc[o4][tau][0], acc[o4][tau][1]);
            p[1] = pack2(acc[o4][tau][2], acc[o4][tau][3]);
        }
    #pragma unroll
    for (int i = 0; i < 4; ++i) {
        uint4 pk = *(const uint4*)&zbuf[(w * 32 + i * 8 + (t >> 3)) * ZSTRIDE + (t & 7) * 8];
        ((uint4*)(zout + (size_t)(n0 + i) * ROW))[t] = pk;
        ((uint2*)(zout8 + (size_t)(n0 + i) * ROW))[t] = pkfp8(pk);
    }
}

// ---------------- pooling over nodes (bf16 raw z, [n][m][c] rows)
__global__ __launch_bounds__(256) void k_pool(const uint* __restrict__ z2, float* __restrict__ pool) {
    int t = blockIdx.x * 256 + threadIdx.x;            // 65536 threads
    float s0 = 0.f, s1 = 0.f;
    for (int u = t; u < N_NODES * ROW / 2; u += 65536) {
        uint v = z2[u];
        s0 += bflo(v); s1 += bfhi(v);
    }
    int k2 = t & 255;                                   // uint index within a row; position = m*64+c
    atomicAdd(&pool[k2 * 2], s0);
    atomicAdd(&pool[k2 * 2 + 1], s1);
}

// ---------------- head: fold layer-4 BN finalize + pool-normalize + linear + sigmoid
__global__ __launch_bounds__(64) void k_out(const float* __restrict__ pool, const float* __restrict__ shadow4,
                                            const float* __restrict__ gamma4, const float* __restrict__ beta4,
                                            const float* __restrict__ wout, const float* __restrict__ bout,
                                            float* __restrict__ out) {
    int c = threadIdx.x;
    float s = 0.f, ss = 0.f;
    #pragma unroll
    for (int j = 0; j < NSHADOW; ++j) { s += shadow4[j * 128 + c]; ss += shadow4[j * 128 + 64 + c]; }
    float mean = s * (1.f / NM);
    float var = ss * (1.f / NM) - mean * mean;
    float a = gamma4[c] * rsqrtf(var + 1e-5f);
    float b = beta4[c] - mean * a;
    float wv = wout[c];
    for (int m = 0; m < 8; ++m) {
        float v = wv * (a * pool[m * 64 + c] * (1.f / N_NODES) + b);
        for (int off = 32; off > 0; off >>= 1) v += __shfl_down(v, off);
        if (c == 0) out[m] = 1.f / (1.f + expf(-(v + bout[0])));
    }
}

extern "C" void kernel_launch(void* const* d_in, const int* in_sizes, int n_in,
                              void* d_out, int out_size, void* d_ws, size_t ws_size,
                              hipStream_t stream) {
    const float* x     = (const float*)d_in[0];
    const int*   ei    = (const int*)d_in[1];
    const int*   srcp  = ei;
    const int*   dstp  = ei + N_EDGES;
    const float* w1_0  = (const float*)d_in[3];
    const float* w1    = (const float*)d_in[4];   // [4][64][64]
    const float* b1    = (const float*)d_in[5];   // [5][64]
    const float* w2    = (const float*)d_in[6];   // [5][64][64]
    const float* b2    = (const float*)d_in[7];
    const float* gamma = (const float*)d_in[8];
    const float* beta  = (const float*)d_in[9];
    const float* wout  = (const float*)d_in[10];
    const float* bout  = (const float*)d_in[11];
    float* out = (float*)d_out;

    char* ws = (char*)d_ws;
    size_t off = 0;
    auto alloc = [&](size_t bytes) -> void* {
        void* p = ws + off;
        off = (off + bytes + 255) & ~(size_t)255;
        return p;
    };
    ushort* zA   = (ushort*)alloc((size_t)N_NODES * ROW * 2);   // 20.5 MB bf16
    ushort* zB   = (ushort*)alloc((size_t)N_NODES * ROW * 2);   // 20.5 MB bf16
    uchar* zA8   = (uchar*)alloc((size_t)N_NODES * ROW);        // 10.25 MB fp8 shadow
    uchar* zB8   = (uchar*)alloc((size_t)N_NODES * ROW);        // 10.25 MB fp8 shadow
    uint4* wfrag = (uint4*)alloc(4608 * 16);                    // pre-packed A-fragments
    // ---- contiguous zero-initialized span: deg, cursor, shadow[5], pool
    int* deg      = (int*)alloc(N_NODES * 4);
    int* cursor   = (int*)alloc(N_NODES * 4);
    float* shadow = (float*)alloc(5 * NSHADOW * 128 * 4);
    float* pool   = (float*)alloc(512 * 4);
    size_t zero_bytes = (size_t)((char*)pool - (char*)deg) + 512 * 4;
    // ---- uninitialized scratch
    int* offs     = (int*)alloc(N_NODES * 4);
    int* esrc     = (int*)alloc(N_EDGES * 4);
    int* csum     = (int*)alloc(NCHUNK * 4);
    int* chunkoff = (int*)alloc(NCHUNK * 4);

    hipMemsetAsync(deg, 0, zero_bytes, stream);

    // CSR build + weight pre-pack
    k_hist<<<(N_EDGES + 255) / 256, 256, 0, stream>>>(dstp, deg);
    k_csum<<<NCHUNK, 256, 0, stream>>>(deg, csum);
    k_cscan<<<1, 128, 0, stream>>>(csum, chunkoff);
    k_chunkscan<<<NCHUNK, 256, 0, stream>>>(deg, chunkoff, offs);
    k_fill<<<(N_EDGES + 255) / 256, 256, 0, stream>>>(srcp, dstp, offs, cursor, esrc);
    k_prep<<<18, 256, 0, stream>>>(w1, w2, wfrag);

    // layer 0 (MFMA, dual-format output)
    k_layer0<<<N_NODES / 16, 256, 0, stream>>>(x, offs, deg, esrc, w1_0, b1, wfrag + 4096, b2,
                                               zA, zA8, shadow);

    // layers 1..4 fused; ping-pong (zA,zA8) <-> (zB,zB8)
    const ushort* zin = zA;  const uchar* zin8 = zA8;
    ushort* zo = zB;         uchar* zo8 = zB8;
    for (int i = 1; i <= 4; ++i) {
        k_layer<<<N_NODES / 16, 256, 0, stream>>>(zin, zin8,
                                                  shadow + (size_t)(i - 1) * NSHADOW * 128,
                                                  gamma + (i - 1) * 64, beta + (i - 1) * 64,
                                                  offs, deg, esrc,
                                                  wfrag + (size_t)(i - 1) * 1024, b1 + i * 64,
                                                  wfrag + (size_t)(i - 1) * 1024 + 512, b2 + i * 64,
                                                  zo, zo8,
                                                  shadow + (size_t)i * NSHADOW * 128);
        const ushort* tz = zin; zin = zo; zo = (ushort*)tz;
        const uchar* t8 = zin8; zin8 = zo8; zo8 = (uchar*)t8;
    }
    // after 4 swaps, final raw z (layer 4) is back in zA

    // head
    k_pool<<<256, 256, 0, stream>>>((const uint*)zA, pool);
    k_out<<<1, 64, 0, stream>>>(pool, shadow + 4 * NSHADOW * 128, gamma + 256, beta + 256, wout, bout, out);
}

// Round 11
// 481.739 us; speedup vs baseline: 1.2210x; 1.0026x over previous
//
#include <hip/hip_runtime.h>

#define N_NODES 20000
#define N_EDGES 320000
#define HID 64
#define MDIM 8
#define ROW 512            // HID*MDIM elements per node row (layout: [n][m][c])
#define NM 160000.0f       // N_NODES*MDIM
#define NCHUNK 79          // ceil(20000/256)
#define NSHADOW 16         // shadow copies per layer
#define ZSTRIDE 72         // shorts per nm-row (64 + 8 pad)

typedef unsigned int uint;
typedef unsigned char uchar;
typedef unsigned short ushort;
typedef __attribute__((ext_vector_type(8))) short bf16x8;
typedef __attribute__((ext_vector_type(4))) float f32x4;
typedef __attribute__((ext_vector_type(2))) float f32x2;

union U4B8 { uint4 u; bf16x8 b; };

__device__ __forceinline__ float bflo(uint u) { return __uint_as_float(u << 16); }
__device__ __forceinline__ float bfhi(uint u) { return __uint_as_float(u & 0xffff0000u); }
__device__ __forceinline__ uint f2bf(float f) {   // round-to-nearest-even
    uint u = __float_as_uint(f);
    return (u + 0x7fffu + ((u >> 16) & 1u)) >> 16;
}
__device__ __forceinline__ uint pack2(float lo, float hi) { return f2bf(lo) | (f2bf(hi) << 16); }
// pack 8 floats (from a bf16x8-packed uint4) into 8 fp8-e4m3 bytes
__device__ __forceinline__ uint2 pkfp8(uint4 pk) {
    int lo = 0, hi = 0;
    lo = __builtin_amdgcn_cvt_pk_fp8_f32(bflo(pk.x), bfhi(pk.x), lo, false);
    lo = __builtin_amdgcn_cvt_pk_fp8_f32(bflo(pk.y), bfhi(pk.y), lo, true);
    hi = __builtin_amdgcn_cvt_pk_fp8_f32(bflo(pk.z), bfhi(pk.z), hi, false);
    hi = __builtin_amdgcn_cvt_pk_fp8_f32(bflo(pk.w), bfhi(pk.w), hi, true);
    uint2 r; r.x = (uint)lo; r.y = (uint)hi; return r;
}

// ---------------- CSR build ----------------
__global__ __launch_bounds__(256) void k_hist(const int* __restrict__ dst, int* __restrict__ deg) {
    int e = blockIdx.x * 256 + threadIdx.x;
    if (e < N_EDGES) atomicAdd(&deg[dst[e]], 1);
}

__global__ __launch_bounds__(256) void k_csum(const int* __restrict__ deg, int* __restrict__ csum) {
    __shared__ int r[256];
    int t = threadIdx.x, i = blockIdx.x * 256 + t;
    r[t] = (i < N_NODES) ? deg[i] : 0;
    __syncthreads();
    for (int s = 128; s > 0; s >>= 1) { if (t < s) r[t] += r[t + s]; __syncthreads(); }
    if (t == 0) csum[blockIdx.x] = r[0];
}

__global__ __launch_bounds__(128) void k_cscan(const int* __restrict__ csum, int* __restrict__ chunkoff) {
    __shared__ int s[128];
    int t = threadIdx.x;
    s[t] = (t < NCHUNK) ? csum[t] : 0;
    __syncthreads();
    if (t == 0) { int run = 0; for (int j = 0; j < NCHUNK; ++j) { int x = s[j]; s[j] = run; run += x; } }
    __syncthreads();
    if (t < NCHUNK) chunkoff[t] = s[t];
}

__global__ __launch_bounds__(256) void k_chunkscan(const int* __restrict__ deg, const int* __restrict__ chunkoff,
                                                   int* __restrict__ offs) {
    __shared__ int sd[256];
    int t = threadIdx.x, i = blockIdx.x * 256 + t;
    int v = (i < N_NODES) ? deg[i] : 0;
    sd[t] = v;
    __syncthreads();
    for (int off = 1; off < 256; off <<= 1) {
        int x = (t >= off) ? sd[t - off] : 0;
        __syncthreads();
        sd[t] += x;
        __syncthreads();
    }
    if (i < N_NODES) offs[i] = sd[t] - v + chunkoff[blockIdx.x];
}

__global__ __launch_bounds__(256) void k_fill(const int* __restrict__ src, const int* __restrict__ dst,
                                              const int* __restrict__ offs, int* __restrict__ cursor,
                                              int* __restrict__ esrc) {
    int e = blockIdx.x * 256 + threadIdx.x;
    if (e < N_EDGES) {
        int d = dst[e];
        int p = atomicAdd(&cursor[d], 1);
        esrc[offs[d] + p] = src[e];
    }
}

// ---------------- pre-pack weights into MFMA A-fragment order (bf16)
// slots 0..4095: layers 1..4, {w1,w2} x 512 ; slots 4096..4607: layer-0 w2
__global__ __launch_bounds__(256) void k_prep(const float* __restrict__ w1, const float* __restrict__ w2,
                                              uint4* __restrict__ wfrag) {
    int id = blockIdx.x * 256 + threadIdx.x;   // 4608 total
    if (id >= 4608) return;
    const float* W;
    int s;
    if (id < 4096) {
        int layer = id >> 10;          // 0..3 -> model layer layer+1
        int rem = id & 1023;
        int which = rem >> 9;          // 0: w1, 1: w2
        s = rem & 511;
        W = which ? &w2[(size_t)(layer + 1) * 4096] : &w1[(size_t)layer * 4096];
    } else {
        s = id - 4096;
        W = w2;                        // layer-0 w2
    }
    int f = s >> 6, l = s & 63;
    int o = (f >> 1) * 16 + (l & 15);
    int c0 = (f & 1) * 32 + (l >> 4) * 8;
    const float* p = &W[o * 64 + c0];
    uint4 a;
    a.x = pack2(p[0], p[1]); a.y = pack2(p[2], p[3]);
    a.z = pack2(p[4], p[5]); a.w = pack2(p[6], p[7]);
    wfrag[id] = a;
}

// ---------------- fused layer 0 (MFMA): gather x (C=1) + rank-1 linear1 in B-frag regs + MFMA linear2
// block = 4 waves x 4 nodes; writes fp8 only
__global__ __launch_bounds__(256) void k_layer0(const float* __restrict__ x, const int* __restrict__ offs,
                                                const int* __restrict__ deg, const int* __restrict__ esrc,
                                                const float* __restrict__ W10, const float* __restrict__ B1,
                                                const uint4* __restrict__ w2f0, const float* __restrict__ B2,
                                                uchar* __restrict__ zout8, float* __restrict__ shadow) {
    __shared__ uint4 w2s[512];
    __shared__ __align__(16) ushort zbuf[128 * ZSTRIDE];
    int tid = threadIdx.x;
    for (int s2 = tid; s2 < 512; s2 += 256) w2s[s2] = w2f0[s2];
    __syncthreads();
    int w = tid >> 6, t = tid & 63;
    int n0 = blockIdx.x * 16 + w * 4;
    int g = t >> 3, m = t & 7;
    // ---- gather zin0 for 4 nodes: 8 neighbor-slots x 8 m per iteration + xor-butterfly
    float zin0v[4];
    #pragma unroll
    for (int i = 0; i < 4; ++i) {
        int n = n0 + i;
        int off = offs[n], dg = deg[n];
        float acc = (t < 8) ? x[n * 8 + t] : 0.f;
        for (int base = 0; base < dg; base += 8) {
            int k = base + g;
            float v = 0.f;
            if (k < dg) { int nb = esrc[off + k]; v = x[(size_t)nb * 8 + m]; }
            acc += v;
        }
        acc += __shfl_xor(acc, 8);
        acc += __shfl_xor(acc, 16);
        acc += __shfl_xor(acc, 32);   // all lanes: zin0[node i][m = t&7]
        zin0v[i] = acc;
    }
    // ---- h = relu(w10*zin0 + b1) built directly in B-frag layout
    bf16x8 bfr[2][2];
    #pragma unroll
    for (int q2 = 0; q2 < 2; ++q2) {
        int kb = q2 * 32 + (t >> 4) * 8;
        float4 wA = *(const float4*)&W10[kb];
        float4 wB = *(const float4*)&W10[kb + 4];
        float4 bA = *(const float4*)&B1[kb];
        float4 bB = *(const float4*)&B1[kb + 4];
        #pragma unroll
        for (int tau = 0; tau < 2; ++tau) {
            float zv = zin0v[tau * 2 + ((t & 15) >> 3)];
            U4B8 u;
            u.u.x = pack2(fmaxf(fmaf(wA.x, zv, bA.x), 0.f), fmaxf(fmaf(wA.y, zv, bA.y), 0.f));
            u.u.y = pack2(fmaxf(fmaf(wA.z, zv, bA.z), 0.f), fmaxf(fmaf(wA.w, zv, bA.w), 0.f));
            u.u.z = pack2(fmaxf(fmaf(wB.x, zv, bB.x), 0.f), fmaxf(fmaf(wB.y, zv, bB.y), 0.f));
            u.u.w = pack2(fmaxf(fmaf(wB.z, zv, bB.z), 0.f), fmaxf(fmaf(wB.w, zv, bB.w), 0.f));
            bfr[q2][tau] = u.b;
        }
    }
    // ---- linear2 via MFMA
    f32x4 acc[4][2];
    #pragma unroll
    for (int o4 = 0; o4 < 4; ++o4) {
        float4 bv = *(const float4*)&B2[o4 * 16 + (t >> 4) * 4];
        #pragma unroll
        for (int tau = 0; tau < 2; ++tau) acc[o4][tau] = (f32x4){bv.x, bv.y, bv.z, bv.w};
    }
    #pragma unroll
    for (int o4 = 0; o4 < 4; ++o4)
        #pragma unroll
        for (int q2 = 0; q2 < 2; ++q2) {
            U4B8 a; a.u = w2s[(o4 * 2 + q2) * 64 + t];
            #pragma unroll
            for (int tau = 0; tau < 2; ++tau)
                acc[o4][tau] = __builtin_amdgcn_mfma_f32_16x16x32_bf16(a.b, bfr[q2][tau], acc[o4][tau], 0, 0, 0);
        }
    #pragma unroll
    for (int o4 = 0; o4 < 4; ++o4)
        #pragma unroll
        for (int tau = 0; tau < 2; ++tau) {
            acc[o4][tau][0] = fmaxf(acc[o4][tau][0], 0.f);
            acc[o4][tau][1] = fmaxf(acc[o4][tau][1], 0.f);
            acc[o4][tau][2] = fmaxf(acc[o4][tau][2], 0.f);
            acc[o4][tau][3] = fmaxf(acc[o4][tau][3], 0.f);
        }
    // BN stats
    int sid = (blockIdx.x & (NSHADOW - 1)) * 128;
    #pragma unroll
    for (int o4 = 0; o4 < 4; ++o4)
        #pragma unroll
        for (int r = 0; r < 4; ++r) {
            float x0 = acc[o4][0][r], x1 = acc[o4][1][r];
            float sv = x0 + x1;
            float ssv = x0 * x0 + x1 * x1;
            sv += __shfl_xor(sv, 1);  ssv += __shfl_xor(ssv, 1);
            sv += __shfl_xor(sv, 2);  ssv += __shfl_xor(ssv, 2);
            sv += __shfl_xor(sv, 4);  ssv += __shfl_xor(ssv, 4);
            sv += __shfl_xor(sv, 8);  ssv += __shfl_xor(ssv, 8);
            if ((t & 15) == o4 * 4 + r) {
                int ch = o4 * 16 + (t >> 4) * 4 + r;
                atomicAdd(&shadow[sid + ch], sv);
                atomicAdd(&shadow[sid + 64 + ch], ssv);
            }
        }
    // pack z into zbuf, coalesced fp8 uint2 stores
    #pragma unroll
    for (int o4 = 0; o4 < 4; ++o4)
        #pragma unroll
        for (int tau = 0; tau < 2; ++tau) {
            uint* p = (uint*)&zbuf[(w * 32 + tau * 16 + (t & 15)) * ZSTRIDE + o4 * 16 + (t >> 4) * 4];
            p[0] = pack2(acc[o4][tau][0], acc[o4][tau][1]);
            p[1] = pack2(acc[o4][tau][2], acc[o4][tau][3]);
        }
    #pragma unroll
    for (int i = 0; i < 4; ++i) {
        uint4 pk = *(const uint4*)&zbuf[(w * 32 + i * 8 + (t >> 3)) * ZSTRIDE + (t & 7) * 8];
        ((uint2*)(zout8 + (size_t)(n0 + i) * ROW))[t] = pkfp8(pk);
    }
}

// ---------------- fused layer (1..4): per-block BN finalize + fp8 gather (ILP4) + MFMA MLP (LDS weights)
__global__ __launch_bounds__(256) void k_layer(const uchar* __restrict__ zprev8,
                                               const float* __restrict__ shadow_prev,
                                               const float* __restrict__ gammaP, const float* __restrict__ betaP,
                                               const int* __restrict__ offs, const int* __restrict__ deg,
                                               const int* __restrict__ esrc,
                                               const uint4* __restrict__ w1f, const float* __restrict__ B1,
                                               const uint4* __restrict__ w2f, const float* __restrict__ B2,
                                               uchar* __restrict__ zout8, float* __restrict__ shadow) {
    __shared__ uint4 w1s[512];
    __shared__ uint4 w2s[512];
    __shared__ __align__(16) ushort zbuf[128 * ZSTRIDE];
    __shared__ float red[128];
    __shared__ __align__(16) float abl[128];
    int tid = threadIdx.x;
    // stage pre-packed weight A-frags into LDS (decouple lgkm from gather vmcnt)
    for (int s2 = tid; s2 < 512; s2 += 256) { w1s[s2] = w1f[s2]; w2s[s2] = w2f[s2]; }
    // per-block redundant BN finalize of previous layer
    if (tid < 128) {
        float s = 0.f;
        #pragma unroll
        for (int j = 0; j < NSHADOW; ++j) s += shadow_prev[j * 128 + tid];
        red[tid] = s;
    }
    __syncthreads();
    if (tid < 64) {
        float mean = red[tid] * (1.f / NM);
        float var = red[64 + tid] * (1.f / NM) - mean * mean;
        float a = gammaP[tid] * rsqrtf(var + 1e-5f);
        abl[tid] = a;
        abl[64 + tid] = betaP[tid] - mean * a;
    }
    __syncthreads();
    int w = tid >> 6, t = tid & 63;
    int n0 = blockIdx.x * 16 + w * 4;
    const float4* abp = (const float4*)abl;
    float4 Alo = abp[(t & 7) * 2], Ahi = abp[(t & 7) * 2 + 1];
    float4 Blo = abp[16 + (t & 7) * 2], Bhi = abp[16 + (t & 7) * 2 + 1];
    // ---- gather 4 nodes (wave-private): all rows fp8, 4-way ILP
    for (int i = 0; i < 4; ++i) {
        int n = n0 + i;
        int off = offs[n], dg = deg[n];
        uint2 sv = ((const uint2*)(zprev8 + (size_t)n * ROW))[t];
        f32x2 s0 = __builtin_amdgcn_cvt_pk_f32_fp8((int)sv.x, false);
        f32x2 s1 = __builtin_amdgcn_cvt_pk_f32_fp8((int)sv.x, true);
        f32x2 s2 = __builtin_amdgcn_cvt_pk_f32_fp8((int)sv.y, false);
        f32x2 s3 = __builtin_amdgcn_cvt_pk_f32_fp8((int)sv.y, true);
        float a0 = s0.x, a1 = s0.y, a2 = s1.x, a3 = s1.y;
        float a4 = s2.x, a5 = s2.y, a6 = s3.x, a7 = s3.y;
        for (int base = 0; base < dg; base += 64) {
            int rem = dg - base;
            int cnt = rem < 64 ? rem : 64;
            int idx = (t < cnt) ? esrc[off + base + t] : 0;
            int j = 0;
            for (; j + 3 < cnt; j += 4) {
                int nb0 = __builtin_amdgcn_readlane(idx, j);
                int nb1 = __builtin_amdgcn_readlane(idx, j + 1);
                int nb2 = __builtin_amdgcn_readlane(idx, j + 2);
                int nb3 = __builtin_amdgcn_readlane(idx, j + 3);
                uint2 r0 = ((const uint2*)(zprev8 + (size_t)nb0 * ROW))[t];
                uint2 r1 = ((const uint2*)(zprev8 + (size_t)nb1 * ROW))[t];
                uint2 r2 = ((const uint2*)(zprev8 + (size_t)nb2 * ROW))[t];
                uint2 r3 = ((const uint2*)(zprev8 + (size_t)nb3 * ROW))[t];
                f32x2 p0, p1, p2, p3;
                p0 = __builtin_amdgcn_cvt_pk_f32_fp8((int)r0.x, false);
                p1 = __builtin_amdgcn_cvt_pk_f32_fp8((int)r0.x, true);
                p2 = __builtin_amdgcn_cvt_pk_f32_fp8((int)r0.y, false);
                p3 = __builtin_amdgcn_cvt_pk_f32_fp8((int)r0.y, true);
                a0 += p0.x; a1 += p0.y; a2 += p1.x; a3 += p1.y;
                a4 += p2.x; a5 += p2.y; a6 += p3.x; a7 += p3.y;
                p0 = __builtin_amdgcn_cvt_pk_f32_fp8((int)r1.x, false);
                p1 = __builtin_amdgcn_cvt_pk_f32_fp8((int)r1.x, true);
                p2 = __builtin_amdgcn_cvt_pk_f32_fp8((int)r1.y, false);
                p3 = __builtin_amdgcn_cvt_pk_f32_fp8((int)r1.y, true);
                a0 += p0.x; a1 += p0.y; a2 += p1.x; a3 += p1.y;
                a4 += p2.x; a5 += p2.y; a6 += p3.x; a7 += p3.y;
                p0 = __builtin_amdgcn_cvt_pk_f32_fp8((int)r2.x, false);
                p1 = __builtin_amdgcn_cvt_pk_f32_fp8((int)r2.x, true);
                p2 = __builtin_amdgcn_cvt_pk_f32_fp8((int)r2.y, false);
                p3 = __builtin_amdgcn_cvt_pk_f32_fp8((int)r2.y, true);
                a0 += p0.x; a1 += p0.y; a2 += p1.x; a3 += p1.y;
                a4 += p2.x; a5 += p2.y; a6 += p3.x; a7 += p3.y;
                p0 = __builtin_amdgcn_cvt_pk_f32_fp8((int)r3.x, false);
                p1 = __builtin_amdgcn_cvt_pk_f32_fp8((int)r3.x, true);
                p2 = __builtin_amdgcn_cvt_pk_f32_fp8((int)r3.y, false);
                p3 = __builtin_amdgcn_cvt_pk_f32_fp8((int)r3.y, true);
                a0 += p0.x; a1 += p0.y; a2 += p1.x; a3 += p1.y;
                a4 += p2.x; a5 += p2.y; a6 += p3.x; a7 += p3.y;
            }
            for (; j < cnt; ++j) {
                int nb = __builtin_amdgcn_readlane(idx, j);
                uint2 r = ((const uint2*)(zprev8 + (size_t)nb * ROW))[t];
                f32x2 p0 = __builtin_amdgcn_cvt_pk_f32_fp8((int)r.x, false);
                f32x2 p1 = __builtin_amdgcn_cvt_pk_f32_fp8((int)r.x, true);
                f32x2 p2 = __builtin_amdgcn_cvt_pk_f32_fp8((int)r.y, false);
                f32x2 p3 = __builtin_amdgcn_cvt_pk_f32_fp8((int)r.y, true);
                a0 += p0.x; a1 += p0.y; a2 += p1.x; a3 += p1.y;
                a4 += p2.x; a5 += p2.y; a6 += p3.x; a7 += p3.y;
            }
        }
        float dp1 = (float)(dg + 1);
        uint4 pk;
        pk.x = pack2(fmaf(Alo.x, a0, Blo.x * dp1), fmaf(Alo.y, a1, Blo.y * dp1));
        pk.y = pack2(fmaf(Alo.z, a2, Blo.z * dp1), fmaf(Alo.w, a3, Blo.w * dp1));
        pk.z = pack2(fmaf(Ahi.x, a4, Bhi.x * dp1), fmaf(Ahi.y, a5, Bhi.y * dp1));
        pk.w = pack2(fmaf(Ahi.z, a6, Bhi.z * dp1), fmaf(Ahi.w, a7, Bhi.w * dp1));
        *(uint4*)&zbuf[(w * 32 + i * 8 + (t >> 3)) * ZSTRIDE + (t & 7) * 8] = pk;
    }
    // ---- MLP via MFMA: D[64 o x 32 nm] per wave; weights from LDS
    bf16x8 bfr[2][2];
    #pragma unroll
    for (int tau = 0; tau < 2; ++tau)
        #pragma unroll
        for (int q2 = 0; q2 < 2; ++q2) {
            U4B8 u;
            u.u = *(const uint4*)&zbuf[(w * 32 + tau * 16 + (t & 15)) * ZSTRIDE + q2 * 32 + (t >> 4) * 8];
            bfr[q2][tau] = u.b;
        }
    f32x4 acc[4][2];
    #pragma unroll
    for (int o4 = 0; o4 < 4; ++o4) {
        float4 bv = *(const float4*)&B1[o4 * 16 + (t >> 4) * 4];
        #pragma unroll
        for (int tau = 0; tau < 2; ++tau) acc[o4][tau] = (f32x4){bv.x, bv.y, bv.z, bv.w};
    }
    #pragma unroll
    for (int o4 = 0; o4 < 4; ++o4)
        #pragma unroll
        for (int q2 = 0; q2 < 2; ++q2) {
            U4B8 a; a.u = w1s[(o4 * 2 + q2) * 64 + t];
            #pragma unroll
            for (int tau = 0; tau < 2; ++tau)
                acc[o4][tau] = __builtin_amdgcn_mfma_f32_16x16x32_bf16(a.b, bfr[q2][tau], acc[o4][tau], 0, 0, 0);
        }
    #pragma unroll
    for (int o4 = 0; o4 < 4; ++o4)
        #pragma unroll
        for (int tau = 0; tau < 2; ++tau) {
            f32x4 v = acc[o4][tau];
            float h0 = fmaxf(v[0], 0.f), h1 = fmaxf(v[1], 0.f), h2 = fmaxf(v[2], 0.f), h3 = fmaxf(v[3], 0.f);
            uint* p = (uint*)&zbuf[(w * 32 + tau * 16 + (t & 15)) * ZSTRIDE + o4 * 16 + (t >> 4) * 4];
            p[0] = pack2(h0, h1); p[1] = pack2(h2, h3);
        }
    #pragma unroll
    for (int tau = 0; tau < 2; ++tau)
        #pragma unroll
        for (int q2 = 0; q2 < 2; ++q2) {
            U4B8 u;
            u.u = *(const uint4*)&zbuf[(w * 32 + tau * 16 + (t & 15)) * ZSTRIDE + q2 * 32 + (t >> 4) * 8];
            bfr[q2][tau] = u.b;
        }
    #pragma unroll
    for (int o4 = 0; o4 < 4; ++o4) {
        float4 bv = *(const float4*)&B2[o4 * 16 + (t >> 4) * 4];
        #pragma unroll
        for (int tau = 0; tau < 2; ++tau) acc[o4][tau] = (f32x4){bv.x, bv.y, bv.z, bv.w};
    }
    #pragma unroll
    for (int o4 = 0; o4 < 4; ++o4)
        #pragma unroll
        for (int q2 = 0; q2 < 2; ++q2) {
            U4B8 a; a.u = w2s[(o4 * 2 + q2) * 64 + t];
            #pragma unroll
            for (int tau = 0; tau < 2; ++tau)
                acc[o4][tau] = __builtin_amdgcn_mfma_f32_16x16x32_bf16(a.b, bfr[q2][tau], acc[o4][tau], 0, 0, 0);
        }
    #pragma unroll
    for (int o4 = 0; o4 < 4; ++o4)
        #pragma unroll
        for (int tau = 0; tau < 2; ++tau) {
            acc[o4][tau][0] = fmaxf(acc[o4][tau][0], 0.f);
            acc[o4][tau][1] = fmaxf(acc[o4][tau][1], 0.f);
            acc[o4][tau][2] = fmaxf(acc[o4][tau][2], 0.f);
            acc[o4][tau][3] = fmaxf(acc[o4][tau][3], 0.f);
        }
    // BN stats: butterfly over 16-lane column group, 2 predicated atomics per matching lane
    int sid = (blockIdx.x & (NSHADOW - 1)) * 128;
    #pragma unroll
    for (int o4 = 0; o4 < 4; ++o4)
        #pragma unroll
        for (int r = 0; r < 4; ++r) {
            float x0 = acc[o4][0][r], x1 = acc[o4][1][r];
            float sv = x0 + x1;
            float ssv = x0 * x0 + x1 * x1;
            sv += __shfl_xor(sv, 1);  ssv += __shfl_xor(ssv, 1);
            sv += __shfl_xor(sv, 2);  ssv += __shfl_xor(ssv, 2);
            sv += __shfl_xor(sv, 4);  ssv += __shfl_xor(ssv, 4);
            sv += __shfl_xor(sv, 8);  ssv += __shfl_xor(ssv, 8);
            if ((t & 15) == o4 * 4 + r) {
                int ch = o4 * 16 + (t >> 4) * 4 + r;
                atomicAdd(&shadow[sid + ch], sv);
                atomicAdd(&shadow[sid + 64 + ch], ssv);
            }
        }
    // pack z2 into zbuf, then coalesced fp8 stores per node
    #pragma unroll
    for (int o4 = 0; o4 < 4; ++o4)
        #pragma unroll
        for (int tau = 0; tau < 2; ++tau) {
            uint* p = (uint*)&zbuf[(w * 32 + tau * 16 + (t & 15)) * ZSTRIDE + o4 * 16 + (t >> 4) * 4];
            p[0] = pack2(acc[o4][tau][0], acc[o4][tau][1]);
            p[1] = pack2(acc[o4][tau][2], acc[o4][tau][3]);
        }
    #pragma unroll
    for (int i = 0; i < 4; ++i) {
        uint4 pk = *(const uint4*)&zbuf[(w * 32 + i * 8 + (t >> 3)) * ZSTRIDE + (t & 7) * 8];
        ((uint2*)(zout8 + (size_t)(n0 + i) * ROW))[t] = pkfp8(pk);
    }
}

// ---------------- pooling over nodes (fp8 raw z, [n][m][c] rows)
__global__ __launch_bounds__(256) void k_pool(const uint* __restrict__ z8, float* __restrict__ pool) {
    int t = blockIdx.x * 256 + threadIdx.x;            // 65536 threads
    float s0 = 0.f, s1 = 0.f, s2 = 0.f, s3 = 0.f;
    for (int u = t; u < N_NODES * ROW / 4; u += 65536) {
        uint v = z8[u];
        f32x2 p0 = __builtin_amdgcn_cvt_pk_f32_fp8((int)v, false);
        f32x2 p1 = __builtin_amdgcn_cvt_pk_f32_fp8((int)v, true);
        s0 += p0.x; s1 += p0.y; s2 += p1.x; s3 += p1.y;
    }
    int k4 = t & 127;                                   // uint index within a row; elem position = m*64+c
    atomicAdd(&pool[k4 * 4 + 0], s0);
    atomicAdd(&pool[k4 * 4 + 1], s1);
    atomicAdd(&pool[k4 * 4 + 2], s2);
    atomicAdd(&pool[k4 * 4 + 3], s3);
}

// ---------------- head: fold layer-4 BN finalize + pool-normalize + linear + sigmoid
__global__ __launch_bounds__(64) void k_out(const float* __restrict__ pool, const float* __restrict__ shadow4,
                                            const float* __restrict__ gamma4, const float* __restrict__ beta4,
                                            const float* __restrict__ wout, const float* __restrict__ bout,
                                            float* __restrict__ out) {
    int c = threadIdx.x;
    float s = 0.f, ss = 0.f;
    #pragma unroll
    for (int j = 0; j < NSHADOW; ++j) { s += shadow4[j * 128 + c]; ss += shadow4[j * 128 + 64 + c]; }
    float mean = s * (1.f / NM);
    float var = ss * (1.f / NM) - mean * mean;
    float a = gamma4[c] * rsqrtf(var + 1e-5f);
    float b = beta4[c] - mean * a;
    float wv = wout[c];
    for (int m = 0; m < 8; ++m) {
        float v = wv * (a * pool[m * 64 + c] * (1.f / N_NODES) + b);
        for (int off = 32; off > 0; off >>= 1) v += __shfl_down(v, off);
        if (c == 0) out[m] = 1.f / (1.f + expf(-(v + bout[0])));
    }
}

extern "C" void kernel_launch(void* const* d_in, const int* in_sizes, int n_in,
                              void* d_out, int out_size, void* d_ws, size_t ws_size,
                              hipStream_t stream) {
    const float* x     = (const float*)d_in[0];
    const int*   ei    = (const int*)d_in[1];
    const int*   srcp  = ei;
    const int*   dstp  = ei + N_EDGES;
    const float* w1_0  = (const float*)d_in[3];
    const float* w1    = (const float*)d_in[4];   // [4][64][64]
    const float* b1    = (const float*)d_in[5];   // [5][64]
    const float* w2    = (const float*)d_in[6];   // [5][64][64]
    const float* b2    = (const float*)d_in[7];
    const float* gamma = (const float*)d_in[8];
    const float* beta  = (const float*)d_in[9];
    const float* wout  = (const float*)d_in[10];
    const float* bout  = (const float*)d_in[11];
    float* out = (float*)d_out;

    char* ws = (char*)d_ws;
    size_t off = 0;
    auto alloc = [&](size_t bytes) -> void* {
        void* p = ws + off;
        off = (off + bytes + 255) & ~(size_t)255;
        return p;
    };
    uchar* zA8   = (uchar*)alloc((size_t)N_NODES * ROW);        // 10.25 MB fp8
    uchar* zB8   = (uchar*)alloc((size_t)N_NODES * ROW);        // 10.25 MB fp8
    uint4* wfrag = (uint4*)alloc(4608 * 16);                    // pre-packed A-fragments
    // ---- contiguous zero-initialized span: deg, cursor, shadow[5], pool
    int* deg      = (int*)alloc(N_NODES * 4);
    int* cursor   = (int*)alloc(N_NODES * 4);
    float* shadow = (float*)alloc(5 * NSHADOW * 128 * 4);
    float* pool   = (float*)alloc(512 * 4);
    size_t zero_bytes = (size_t)((char*)pool - (char*)deg) + 512 * 4;
    // ---- uninitialized scratch
    int* offs     = (int*)alloc(N_NODES * 4);
    int* esrc     = (int*)alloc(N_EDGES * 4);
    int* csum     = (int*)alloc(NCHUNK * 4);
    int* chunkoff = (int*)alloc(NCHUNK * 4);

    hipMemsetAsync(deg, 0, zero_bytes, stream);

    // CSR build + weight pre-pack
    k_hist<<<(N_EDGES + 255) / 256, 256, 0, stream>>>(dstp, deg);
    k_csum<<<NCHUNK, 256, 0, stream>>>(deg, csum);
    k_cscan<<<1, 128, 0, stream>>>(csum, chunkoff);
    k_chunkscan<<<NCHUNK, 256, 0, stream>>>(deg, chunkoff, offs);
    k_fill<<<(N_EDGES + 255) / 256, 256, 0, stream>>>(srcp, dstp, offs, cursor, esrc);
    k_prep<<<18, 256, 0, stream>>>(w1, w2, wfrag);

    // layer 0 (MFMA, fp8 output)
    k_layer0<<<N_NODES / 16, 256, 0, stream>>>(x, offs, deg, esrc, w1_0, b1, wfrag + 4096, b2,
                                               zA8, shadow);

    // layers 1..4 fused; ping-pong zA8 <-> zB8
    const uchar* zin8 = zA8;
    uchar* zo8 = zB8;
    for (int i = 1; i <= 4; ++i) {
        k_layer<<<N_NODES / 16, 256, 0, stream>>>(zin8,
                                                  shadow + (size_t)(i - 1) * NSHADOW * 128,
                                                  gamma + (i - 1) * 64, beta + (i - 1) * 64,
                                                  offs, deg, esrc,
                                                  wfrag + (size_t)(i - 1) * 1024, b1 + i * 64,
                                                  wfrag + (size_t)(i - 1) * 1024 + 512, b2 + i * 64,
                                                  zo8,
                                                  shadow + (size_t)i * NSHADOW * 128);
        const uchar* t8 = zin8; zin8 = zo8; zo8 = (uchar*)t8;
    }
    // after 4 swaps, final raw z (layer 4) is back in zA8

    // head
    k_pool<<<256, 256, 0, stream>>>((const uint*)zA8, pool);
    k_out<<<1, 64, 0, stream>>>(pool, shadow + 4 * NSHADOW * 128, gamma + 256, beta + 256, wout, bout, out);
}